// Round 6
// baseline (377.765 us; speedup 1.0000x reference)
//
#include <hip/hip_runtime.h>
#include <hip/hip_bf16.h>
#include <hip/hip_cooperative_groups.h>
#include <math.h>

namespace cg = cooperative_groups;

typedef float  f32x4  __attribute__((ext_vector_type(4)));
typedef short  s16x4  __attribute__((ext_vector_type(4)));
typedef short  s16x8  __attribute__((ext_vector_type(8)));
typedef unsigned short u16;

__device__ inline u16 f2b(float f) {
    __hip_bfloat16 h = __float2bfloat16(f);
    return *reinterpret_cast<u16*>(&h);
}

// LDS: one union, max 53248 B -> 2 blocks/CU co-resident (160 KiB budget).
struct GemmSh { u16 A[64][72]; u16 B[64][72]; float O[64][68]; }; // 35840 B
struct AttnSh { u16 K[192][72]; u16 V[64][200]; };                // 53248 B
union ShU { GemmSh g; AttnSh a; u16 T[64][72]; };

// ---------------------------------------------------------------------------
// Cooperative mega-kernel: P0 prep -> P1 QKV GEMM+RoPE/RMS -> P2 SWA -> P3
// O-proj, with grid.sync() between phases. 512 blocks x 256 threads.
// Phase bodies are the verified round-5 kernels.
// ---------------------------------------------------------------------------
__global__ __launch_bounds__(256, 2) void mega(
    const float* __restrict__ x,  const float* __restrict__ Wq,
    const float* __restrict__ Wk, const float* __restrict__ Wv,
    const float* __restrict__ Wo, const float* __restrict__ qw,
    const float* __restrict__ kw, const float* __restrict__ cosT,
    const float* __restrict__ sinT, u16* __restrict__ ws,
    float* __restrict__ out)
{
    __shared__ ShU sh;
    u16* xb   = ws;                              // 2048*512
    u16* Wt   = xb   + (size_t)2048 * 512;       // 1024*512
    u16* Wot  = Wt   + (size_t)1024 * 512;       // 512*512
    u16* qnb  = Wot  + (size_t)512 * 512;        // 2048*512
    u16* knb  = qnb  + (size_t)2048 * 512;       // 2048*256
    u16* vb   = knb  + (size_t)2048 * 256;       // 2048*256
    u16* attb = vb   + (size_t)2048 * 256;       // 2048*512

    const int tid = threadIdx.x, bid = blockIdx.x;
    const int lane = tid & 63, wv = tid >> 6;
    const int q = lane & 15, g = lane >> 4;
    cg::grid_group grid = cg::this_grid();

    // ---------------- P0: x cast (all 512 blocks) + weight transpose (0-191)
    {
        int i = (bid * 256 + tid) * 8;           // 512*256*8 = 2048*512 exactly
        float4 v0 = *(const float4*)(x + i);
        float4 v1 = *(const float4*)(x + i + 4);
        ushort4 o0 = { f2b(v0.x), f2b(v0.y), f2b(v0.z), f2b(v0.w) };
        ushort4 o1 = { f2b(v1.x), f2b(v1.y), f2b(v1.z), f2b(v1.w) };
        *(ushort4*)(xb + i)     = o0;
        *(ushort4*)(xb + i + 4) = o1;
        if (bid < 192) {
            const float* src; u16* dst; int N, base, kt, nt;
            if (bid < 64)       { src = Wq; dst = Wt;  N = 512; base = 0;   kt = bid >> 3;       nt = bid & 7; }
            else if (bid < 96)  { src = Wk; dst = Wt;  N = 256; base = 512; kt = (bid-64) >> 2;  nt = (bid-64) & 3; }
            else if (bid < 128) { src = Wv; dst = Wt;  N = 256; base = 768; kt = (bid-96) >> 2;  nt = (bid-96) & 3; }
            else                { src = Wo; dst = Wot; N = 512; base = 0;   kt = (bid-128) >> 3; nt = (bid-128) & 7; }
            const int k0 = kt * 64, n0 = nt * 64;
            const int r = tid >> 2, c0 = (tid & 3) * 16;
#pragma unroll
            for (int j = 0; j < 4; ++j) {
                float4 v = *(const float4*)(src + (size_t)(k0 + r) * N + n0 + c0 + j * 4);
                sh.T[c0 + j*4 + 0][r] = f2b(v.x);
                sh.T[c0 + j*4 + 1][r] = f2b(v.y);
                sh.T[c0 + j*4 + 2][r] = f2b(v.z);
                sh.T[c0 + j*4 + 3][r] = f2b(v.w);
            }
            __syncthreads();
            const int n = tid >> 2, kc = (tid & 3) * 16;
            u16* op = dst + (size_t)(base + n0 + n) * 512 + k0 + kc;
            *(s16x8*)(op)     = *(const s16x8*)&sh.T[n][kc];
            *(s16x8*)(op + 8) = *(const s16x8*)&sh.T[n][kc + 8];
        }
    }
    __threadfence();
    grid.sync();

    // ---------------- P1: QKV GEMM + fused RoPE/RMS epilogue (all 512 blocks)
    {
        const int bx = bid & 15;                 // n-tile: 0-7 q, 8-11 k, 12-15 v
        const int m0 = (bid >> 4) * 64, n0b = bx * 64;
        const int wm = (wv & 1) * 32, wn = (wv >> 1) * 32;
        const int sr = tid >> 2, sc = (tid & 3) * 16;
        f32x4 acc[2][2] = {{{0,0,0,0},{0,0,0,0}},{{0,0,0,0},{0,0,0,0}}};
        for (int k0 = 0; k0 < 512; k0 += 64) {
            s16x8 a0 = *(const s16x8*)(xb + (size_t)(m0 + sr)  * 512 + k0 + sc);
            s16x8 a1 = *(const s16x8*)(xb + (size_t)(m0 + sr)  * 512 + k0 + sc + 8);
            s16x8 b0 = *(const s16x8*)(Wt + (size_t)(n0b + sr) * 512 + k0 + sc);
            s16x8 b1 = *(const s16x8*)(Wt + (size_t)(n0b + sr) * 512 + k0 + sc + 8);
            __syncthreads();
            *(s16x8*)&sh.g.A[sr][sc]     = a0;
            *(s16x8*)&sh.g.A[sr][sc + 8] = a1;
            *(s16x8*)&sh.g.B[sr][sc]     = b0;
            *(s16x8*)&sh.g.B[sr][sc + 8] = b1;
            __syncthreads();
#pragma unroll
            for (int kk = 0; kk < 64; kk += 32) {
                s16x8 af0 = *(const s16x8*)&sh.g.A[wm + q][kk + g*8];
                s16x8 af1 = *(const s16x8*)&sh.g.A[wm + 16 + q][kk + g*8];
                s16x8 bf0 = *(const s16x8*)&sh.g.B[wn + q][kk + g*8];
                s16x8 bf1 = *(const s16x8*)&sh.g.B[wn + 16 + q][kk + g*8];
                acc[0][0] = __builtin_amdgcn_mfma_f32_16x16x32_bf16(af0, bf0, acc[0][0], 0, 0, 0);
                acc[0][1] = __builtin_amdgcn_mfma_f32_16x16x32_bf16(af0, bf1, acc[0][1], 0, 0, 0);
                acc[1][0] = __builtin_amdgcn_mfma_f32_16x16x32_bf16(af1, bf0, acc[1][0], 0, 0, 0);
                acc[1][1] = __builtin_amdgcn_mfma_f32_16x16x32_bf16(af1, bf1, acc[1][1], 0, 0, 0);
            }
        }
        __syncthreads();
#pragma unroll
        for (int mt = 0; mt < 2; ++mt)
#pragma unroll
            for (int nt = 0; nt < 2; ++nt)
#pragma unroll
                for (int r = 0; r < 4; ++r)
                    sh.g.O[wm + mt*16 + g*4 + r][wn + nt*16 + q] = acc[mt][nt][r];
        __syncthreads();
#pragma unroll 1
        for (int ii = 0; ii < 16; ++ii) {
            const int row = wv * 16 + ii;
            const int t = m0 + row;
            if (bx >= 12) {
                vb[(size_t)t * 256 + (bx - 12) * 64 + lane] = f2b(sh.g.O[row][lane]);
                continue;
            }
            float y = sh.g.O[row][lane];
            float o = sh.g.O[row][lane ^ 32];
            float c = cosT[t * 32 + (lane & 31)];
            float s = sinT[t * 32 + (lane & 31)];
            float r = (lane < 32) ? (y * c - o * s) : (y * c + o * s);
            float ss = r * r;
#pragma unroll
            for (int off = 32; off; off >>= 1) ss += __shfl_xor(ss, off);
            float scale = rsqrtf(ss * (1.0f / 64.0f) + 1e-6f);
            if (bx < 8) qnb[(size_t)t * 512 + bx * 64 + lane]       = f2b(r * scale * qw[lane]);
            else        knb[(size_t)t * 256 + (bx - 8) * 64 + lane] = f2b(r * scale * kw[lane]);
        }
    }
    __threadfence();
    grid.sync();

    // ---------------- P2: sliding-window attention (blocks 0-255)
    if (bid < 256) {
        const int h = bid >> 5, kvh = h >> 1;
        const int t0 = (bid & 31) * 64;
        for (int i = 0; i < 6; ++i) {
            int idx = i * 256 + tid;
            int j = idx >> 3, d0 = (idx & 7) * 8;
            int kt = t0 - 127 + j;
            s16x8 val = {0,0,0,0,0,0,0,0};
            if (kt >= 0) val = *(const s16x8*)(knb + (size_t)kt * 256 + kvh * 64 + d0);
            *(s16x8*)&sh.a.K[j][d0] = val;
        }
        for (int cch = 0; cch < 6; ++cch) {
            int w  = cch * 32 + (tid & 31);
            int d0 = (tid >> 5) * 8;
            int kt = t0 - 127 + w;
            s16x8 val = {0,0,0,0,0,0,0,0};
            if (kt >= 0) val = *(const s16x8*)(vb + (size_t)kt * 256 + kvh * 64 + d0);
#pragma unroll
            for (int jj = 0; jj < 8; ++jj) sh.a.V[d0 + jj][w] = ((const u16*)&val)[jj];
        }
        __syncthreads();
        const int tw = t0 + wv * 16;
        const int t = tw + q;
        const u16* qp = qnb + (size_t)t * 512 + h * 64;
        s16x8 qf0 = *(const s16x8*)(qp + g * 8);
        s16x8 qf1 = *(const s16x8*)(qp + 32 + g * 8);
        float s[9][4];
        float mx = -INFINITY;
        for (int wt = 0; wt < 9; ++wt) {
            int ldsrow = wv * 16 + wt * 16 + q;
            s16x8 kf0 = *(const s16x8*)&sh.a.K[ldsrow][g * 8];
            s16x8 kf1 = *(const s16x8*)&sh.a.K[ldsrow][32 + g * 8];
            f32x4 accv = {0, 0, 0, 0};
            accv = __builtin_amdgcn_mfma_f32_16x16x32_bf16(kf0, qf0, accv, 0, 0, 0);
            accv = __builtin_amdgcn_mfma_f32_16x16x32_bf16(kf1, qf1, accv, 0, 0, 0);
#pragma unroll
            for (int r = 0; r < 4; ++r) {
                int woff = wt * 16 + g * 4 + r;
                int key  = tw - 127 + woff;
                bool ok = (woff >= q) && (woff <= q + 127) && (key >= 0);
                float sv = ok ? accv[r] * 0.125f : -INFINITY;
                s[wt][r] = sv;
                mx = fmaxf(mx, sv);
            }
        }
        mx = fmaxf(mx, __shfl_xor(mx, 16));
        mx = fmaxf(mx, __shfl_xor(mx, 32));
        float sum = 0.f;
        s16x4 pb[9];
        for (int wt = 0; wt < 9; ++wt) {
#pragma unroll
            for (int r = 0; r < 4; ++r) {
                float p = __expf(s[wt][r] - mx);
                sum += p;
                pb[wt][r] = (short)f2b(p);
            }
        }
        sum += __shfl_xor(sum, 16);
        sum += __shfl_xor(sum, 32);
        float inv = 1.0f / sum;
        f32x4 oacc[4];
#pragma unroll
        for (int dt = 0; dt < 4; ++dt) {
            f32x4 a = {0, 0, 0, 0};
            for (int wt = 0; wt < 9; ++wt) {
                int col = wv * 16 + wt * 16 + g * 4;
                s16x4 vf = *(const s16x4*)&sh.a.V[dt * 16 + q][col];
                a = __builtin_amdgcn_mfma_f32_16x16x16bf16_1k(vf, pb[wt], a, 0, 0, 0);
            }
            oacc[dt] = a;
        }
        __syncthreads();
        float (*Osh)[16][68] = (float (*)[16][68])&sh.a.K[0][0];
#pragma unroll
        for (int dt = 0; dt < 4; ++dt)
#pragma unroll
            for (int r = 0; r < 4; ++r)
                Osh[wv][q][dt * 16 + g * 4 + r] = oacc[dt][r] * inv;
        __syncthreads();
        const int qq = lane >> 2, dd0 = (lane & 3) * 16;
        u16* op = attb + (size_t)(tw + qq) * 512 + h * 64 + dd0;
#pragma unroll
        for (int jj = 0; jj < 4; ++jj) {
            float4 vvv = *(const float4*)&Osh[wv][qq][dd0 + jj * 4];
            ushort4 ov = { f2b(vvv.x), f2b(vvv.y), f2b(vvv.z), f2b(vvv.w) };
            *(ushort4*)(op + jj * 4) = ov;
        }
    }
    __threadfence();
    grid.sync();

    // ---------------- P3: output projection (blocks 0-255)
    if (bid < 256) {
        const int m0 = (bid >> 3) * 64, n0 = (bid & 7) * 64;
        const int wm = (wv & 1) * 32, wn = (wv >> 1) * 32;
        const int sr = tid >> 2, sc = (tid & 3) * 16;
        f32x4 acc[2][2] = {{{0,0,0,0},{0,0,0,0}},{{0,0,0,0},{0,0,0,0}}};
        for (int k0 = 0; k0 < 512; k0 += 64) {
            s16x8 a0 = *(const s16x8*)(attb + (size_t)(m0 + sr) * 512 + k0 + sc);
            s16x8 a1 = *(const s16x8*)(attb + (size_t)(m0 + sr) * 512 + k0 + sc + 8);
            s16x8 b0 = *(const s16x8*)(Wot  + (size_t)(n0 + sr) * 512 + k0 + sc);
            s16x8 b1 = *(const s16x8*)(Wot  + (size_t)(n0 + sr) * 512 + k0 + sc + 8);
            __syncthreads();
            *(s16x8*)&sh.g.A[sr][sc]     = a0;
            *(s16x8*)&sh.g.A[sr][sc + 8] = a1;
            *(s16x8*)&sh.g.B[sr][sc]     = b0;
            *(s16x8*)&sh.g.B[sr][sc + 8] = b1;
            __syncthreads();
#pragma unroll
            for (int kk = 0; kk < 64; kk += 32) {
                s16x8 af0 = *(const s16x8*)&sh.g.A[wm + q][kk + g*8];
                s16x8 af1 = *(const s16x8*)&sh.g.A[wm + 16 + q][kk + g*8];
                s16x8 bf0 = *(const s16x8*)&sh.g.B[wn + q][kk + g*8];
                s16x8 bf1 = *(const s16x8*)&sh.g.B[wn + 16 + q][kk + g*8];
                acc[0][0] = __builtin_amdgcn_mfma_f32_16x16x32_bf16(af0, bf0, acc[0][0], 0, 0, 0);
                acc[0][1] = __builtin_amdgcn_mfma_f32_16x16x32_bf16(af0, bf1, acc[0][1], 0, 0, 0);
                acc[1][0] = __builtin_amdgcn_mfma_f32_16x16x32_bf16(af1, bf0, acc[1][0], 0, 0, 0);
                acc[1][1] = __builtin_amdgcn_mfma_f32_16x16x32_bf16(af1, bf1, acc[1][1], 0, 0, 0);
            }
        }
#pragma unroll
        for (int mt = 0; mt < 2; ++mt)
#pragma unroll
            for (int nt = 0; nt < 2; ++nt)
#pragma unroll
                for (int r = 0; r < 4; ++r)
                    out[(size_t)(m0 + wm + mt*16 + g*4 + r) * 512 + n0 + wn + nt*16 + q] = acc[mt][nt][r];
    }
}

extern "C" void kernel_launch(void* const* d_in, const int* in_sizes, int n_in,
                              void* d_out, int out_size, void* d_ws, size_t ws_size,
                              hipStream_t stream)
{
    const float* x    = (const float*)d_in[0];
    const float* Wq   = (const float*)d_in[1];
    const float* Wk   = (const float*)d_in[2];
    const float* Wv   = (const float*)d_in[3];
    const float* Wo   = (const float*)d_in[4];
    const float* qw   = (const float*)d_in[5];
    const float* kw   = (const float*)d_in[6];
    const float* cosT = (const float*)d_in[7];
    const float* sinT = (const float*)d_in[8];
    u16* ws = (u16*)d_ws;
    float* outp = (float*)d_out;

    void* args[] = {
        (void*)&x, (void*)&Wq, (void*)&Wk, (void*)&Wv, (void*)&Wo,
        (void*)&qw, (void*)&kw, (void*)&cosT, (void*)&sinT,
        (void*)&ws, (void*)&outp
    };
    hipLaunchCooperativeKernel((const void*)mega, dim3(512), dim3(256),
                               args, 0, stream);
}

// Round 7
// 51.395 us; speedup vs baseline: 7.3502x; 7.3502x over previous
//
#include <hip/hip_runtime.h>
#include <hip/hip_bf16.h>
#include <math.h>

typedef float  f32x4  __attribute__((ext_vector_type(4)));
typedef short  s16x4  __attribute__((ext_vector_type(4)));
typedef short  s16x8  __attribute__((ext_vector_type(8)));
typedef unsigned short u16;

__device__ inline u16 f2b(float f) {
    __hip_bfloat16 h = __float2bfloat16(f);
    return *reinterpret_cast<u16*>(&h);
}

// ---------------------------------------------------------------------------
// K0: prep. blocks 0-191: transpose-cast weights -> Wt [1024][512] bf16
// (rows 0-511 Wq^T | 512-767 Wk^T | 768-1023 Wv^T), Wot [512][512] = Wo^T.
// blocks 192-703: cast x -> xb bf16 (8 elems/thread).
// ---------------------------------------------------------------------------
__global__ __launch_bounds__(256) void prep(const float* __restrict__ x,
    const float* __restrict__ Wq, const float* __restrict__ Wk,
    const float* __restrict__ Wv, const float* __restrict__ Wo,
    u16* __restrict__ xb, u16* __restrict__ Wt, u16* __restrict__ Wot)
{
    const int tid = threadIdx.x, bid = blockIdx.x;
    if (bid >= 192) {   // x cast
        int i = ((bid - 192) * 256 + tid) * 8;
        float4 v0 = *(const float4*)(x + i);
        float4 v1 = *(const float4*)(x + i + 4);
        ushort4 o0 = { f2b(v0.x), f2b(v0.y), f2b(v0.z), f2b(v0.w) };
        ushort4 o1 = { f2b(v1.x), f2b(v1.y), f2b(v1.z), f2b(v1.w) };
        *(ushort4*)(xb + i)     = o0;
        *(ushort4*)(xb + i + 4) = o1;
        return;
    }
    __shared__ u16 Tsh[64][72];
    const float* src; u16* dst; int N, base, kt, nt;
    if (bid < 64)       { src = Wq; dst = Wt;  N = 512; base = 0;   kt = bid >> 3;       nt = bid & 7; }
    else if (bid < 96)  { src = Wk; dst = Wt;  N = 256; base = 512; kt = (bid-64) >> 2;  nt = (bid-64) & 3; }
    else if (bid < 128) { src = Wv; dst = Wt;  N = 256; base = 768; kt = (bid-96) >> 2;  nt = (bid-96) & 3; }
    else                { src = Wo; dst = Wot; N = 512; base = 0;   kt = (bid-128) >> 3; nt = (bid-128) & 7; }
    const int k0 = kt * 64, n0 = nt * 64;
    const int r = tid >> 2, c0 = (tid & 3) * 16;
#pragma unroll
    for (int j = 0; j < 4; ++j) {
        float4 v = *(const float4*)(src + (size_t)(k0 + r) * N + n0 + c0 + j * 4);
        Tsh[c0 + j*4 + 0][r] = f2b(v.x);
        Tsh[c0 + j*4 + 1][r] = f2b(v.y);
        Tsh[c0 + j*4 + 2][r] = f2b(v.z);
        Tsh[c0 + j*4 + 3][r] = f2b(v.w);
    }
    __syncthreads();
    const int n = tid >> 2, kc = (tid & 3) * 16;
    u16* op = dst + (size_t)(base + n0 + n) * 512 + k0 + kc;
    *(s16x8*)(op)     = *(const s16x8*)&Tsh[n][kc];
    *(s16x8*)(op + 8) = *(const s16x8*)&Tsh[n][kc + 8];
}

// ---------------------------------------------------------------------------
// K1: QKV GEMM + fused RoPE/RMS epilogue. Double-buffered LDS, ONE barrier
// per K-step; next-tile loads issued after the barrier so they overlap MFMA
// (never drained by the barrier's vmcnt(0)).
// M=2048, N=1024 (16 n-tiles = heads), K=512, 64x64 tile / 4 waves.
// ---------------------------------------------------------------------------
__global__ __launch_bounds__(256) void qkv_gemm(const u16* __restrict__ A,
    const u16* __restrict__ Bt, const float* __restrict__ cosT,
    const float* __restrict__ sinT, const float* __restrict__ qw,
    const float* __restrict__ kw, u16* __restrict__ qnb,
    u16* __restrict__ knb, u16* __restrict__ vb)
{
    __shared__ union {
        struct { u16 A[2][64][72]; u16 B[2][64][72]; } d;   // 36864 B
        float O[64][68];                                     // 17408 B
    } sh;
    const int tid = threadIdx.x;
    const int bx = blockIdx.x;
    const int m0 = blockIdx.y * 64, n0b = bx * 64;
    const int lane = tid & 63, wv = tid >> 6;
    const int q = lane & 15, g = lane >> 4;
    const int wm = (wv & 1) * 32, wn = (wv >> 1) * 32;
    const int sr = tid >> 2, sc = (tid & 3) * 16;
    const u16* Ap = A  + (size_t)(m0 + sr)  * 512 + sc;
    const u16* Bp = Bt + (size_t)(n0b + sr) * 512 + sc;
    {   // stage tile 0 into buf 0
        s16x8 a0 = *(const s16x8*)(Ap);
        s16x8 a1 = *(const s16x8*)(Ap + 8);
        s16x8 b0 = *(const s16x8*)(Bp);
        s16x8 b1 = *(const s16x8*)(Bp + 8);
        *(s16x8*)&sh.d.A[0][sr][sc]     = a0;
        *(s16x8*)&sh.d.A[0][sr][sc + 8] = a1;
        *(s16x8*)&sh.d.B[0][sr][sc]     = b0;
        *(s16x8*)&sh.d.B[0][sr][sc + 8] = b1;
    }
    f32x4 acc[2][2] = {{{0,0,0,0},{0,0,0,0}},{{0,0,0,0},{0,0,0,0}}};
#pragma unroll
    for (int it = 0; it < 8; ++it) {
        const int cur = it & 1;
        __syncthreads();                       // buf[cur] writes visible
        s16x8 a0, a1, b0, b1;
        if (it < 7) {                          // issue next-tile loads (overlap MFMA)
            const u16* An = Ap + (it + 1) * 64;
            const u16* Bn = Bp + (it + 1) * 64;
            a0 = *(const s16x8*)(An);
            a1 = *(const s16x8*)(An + 8);
            b0 = *(const s16x8*)(Bn);
            b1 = *(const s16x8*)(Bn + 8);
        }
#pragma unroll
        for (int kk = 0; kk < 64; kk += 32) {
            s16x8 af0 = *(const s16x8*)&sh.d.A[cur][wm + q][kk + g*8];
            s16x8 af1 = *(const s16x8*)&sh.d.A[cur][wm + 16 + q][kk + g*8];
            s16x8 bf0 = *(const s16x8*)&sh.d.B[cur][wn + q][kk + g*8];
            s16x8 bf1 = *(const s16x8*)&sh.d.B[cur][wn + 16 + q][kk + g*8];
            acc[0][0] = __builtin_amdgcn_mfma_f32_16x16x32_bf16(af0, bf0, acc[0][0], 0, 0, 0);
            acc[0][1] = __builtin_amdgcn_mfma_f32_16x16x32_bf16(af0, bf1, acc[0][1], 0, 0, 0);
            acc[1][0] = __builtin_amdgcn_mfma_f32_16x16x32_bf16(af1, bf0, acc[1][0], 0, 0, 0);
            acc[1][1] = __builtin_amdgcn_mfma_f32_16x16x32_bf16(af1, bf1, acc[1][1], 0, 0, 0);
        }
        if (it < 7) {                          // write next tile to other buf
            *(s16x8*)&sh.d.A[cur ^ 1][sr][sc]     = a0;
            *(s16x8*)&sh.d.A[cur ^ 1][sr][sc + 8] = a1;
            *(s16x8*)&sh.d.B[cur ^ 1][sr][sc]     = b0;
            *(s16x8*)&sh.d.B[cur ^ 1][sr][sc + 8] = b1;
        }
    }
    __syncthreads();                           // all MFMA reads done; reuse LDS as O
#pragma unroll
    for (int mt = 0; mt < 2; ++mt)
#pragma unroll
        for (int nt = 0; nt < 2; ++nt)
#pragma unroll
            for (int r = 0; r < 4; ++r)
                sh.O[wm + mt*16 + g*4 + r][wn + nt*16 + q] = acc[mt][nt][r];
    __syncthreads();
    // Per-row epilogue: wave wv owns rows wv*16..wv*16+15; lane = d
#pragma unroll 1
    for (int ii = 0; ii < 16; ++ii) {
        const int row = wv * 16 + ii;
        const int t = m0 + row;
        if (bx >= 12) {
            vb[(size_t)t * 256 + (bx - 12) * 64 + lane] = f2b(sh.O[row][lane]);
            continue;
        }
        float y = sh.O[row][lane];
        float o = sh.O[row][lane ^ 32];
        float c = cosT[t * 32 + (lane & 31)];
        float s = sinT[t * 32 + (lane & 31)];
        float r = (lane < 32) ? (y * c - o * s) : (y * c + o * s);
        float ss = r * r;
#pragma unroll
        for (int off = 32; off; off >>= 1) ss += __shfl_xor(ss, off);
        float scale = rsqrtf(ss * (1.0f / 64.0f) + 1e-6f);
        if (bx < 8) qnb[(size_t)t * 512 + bx * 64 + lane]       = f2b(r * scale * qw[lane]);
        else        knb[(size_t)t * 256 + (bx - 8) * 64 + lane] = f2b(r * scale * kw[lane]);
    }
}

// ---------------------------------------------------------------------------
// K2: MFMA sliding-window attention (verified, unchanged). Block = (h, 64-q
// tile). S^T = K·Q^T (16x16x32), P^T rows land in 16x16x16 k-operand layout,
// O^T = V^T·P^T, LDS transpose out.
// ---------------------------------------------------------------------------
__global__ __launch_bounds__(256) void swa_mfma(const u16* __restrict__ qnb,
    const u16* __restrict__ knb, const u16* __restrict__ vb,
    u16* __restrict__ attb)
{
    __shared__ u16 Ksh[192][72];
    __shared__ u16 Vt[64][200];
    const int tid = threadIdx.x;
    const int h = blockIdx.y, kvh = h >> 1;
    const int t0 = blockIdx.x * 64;
    for (int i = 0; i < 6; ++i) {
        int idx = i * 256 + tid;
        int j = idx >> 3, d0 = (idx & 7) * 8;
        int kt = t0 - 127 + j;
        s16x8 val = {0,0,0,0,0,0,0,0};
        if (kt >= 0) val = *(const s16x8*)(knb + (size_t)kt * 256 + kvh * 64 + d0);
        *(s16x8*)&Ksh[j][d0] = val;
    }
    for (int cch = 0; cch < 6; ++cch) {
        int w  = cch * 32 + (tid & 31);
        int d0 = (tid >> 5) * 8;
        int kt = t0 - 127 + w;
        s16x8 val = {0,0,0,0,0,0,0,0};
        if (kt >= 0) val = *(const s16x8*)(vb + (size_t)kt * 256 + kvh * 64 + d0);
#pragma unroll
        for (int jj = 0; jj < 8; ++jj) Vt[d0 + jj][w] = ((const u16*)&val)[jj];
    }
    __syncthreads();
    const int wv = tid >> 6, lane = tid & 63;
    const int q = lane & 15, g = lane >> 4;
    const int tw = t0 + wv * 16;
    const int t = tw + q;
    const u16* qp = qnb + (size_t)t * 512 + h * 64;
    s16x8 qf0 = *(const s16x8*)(qp + g * 8);
    s16x8 qf1 = *(const s16x8*)(qp + 32 + g * 8);
    float s[9][4];
    float mx = -INFINITY;
    for (int wt = 0; wt < 9; ++wt) {
        int ldsrow = wv * 16 + wt * 16 + q;
        s16x8 kf0 = *(const s16x8*)&Ksh[ldsrow][g * 8];
        s16x8 kf1 = *(const s16x8*)&Ksh[ldsrow][32 + g * 8];
        f32x4 accv = {0, 0, 0, 0};
        accv = __builtin_amdgcn_mfma_f32_16x16x32_bf16(kf0, qf0, accv, 0, 0, 0);
        accv = __builtin_amdgcn_mfma_f32_16x16x32_bf16(kf1, qf1, accv, 0, 0, 0);
#pragma unroll
        for (int r = 0; r < 4; ++r) {
            int woff = wt * 16 + g * 4 + r;
            int key  = tw - 127 + woff;
            bool ok = (woff >= q) && (woff <= q + 127) && (key >= 0);
            float sv = ok ? accv[r] * 0.125f : -INFINITY;
            s[wt][r] = sv;
            mx = fmaxf(mx, sv);
        }
    }
    mx = fmaxf(mx, __shfl_xor(mx, 16));
    mx = fmaxf(mx, __shfl_xor(mx, 32));
    float sum = 0.f;
    s16x4 pb[9];
    for (int wt = 0; wt < 9; ++wt) {
#pragma unroll
        for (int r = 0; r < 4; ++r) {
            float p = __expf(s[wt][r] - mx);
            sum += p;
            pb[wt][r] = (short)f2b(p);
        }
    }
    sum += __shfl_xor(sum, 16);
    sum += __shfl_xor(sum, 32);
    float inv = 1.0f / sum;
    f32x4 oacc[4];
#pragma unroll
    for (int dt = 0; dt < 4; ++dt) {
        f32x4 a = {0, 0, 0, 0};
        for (int wt = 0; wt < 9; ++wt) {
            int col = wv * 16 + wt * 16 + g * 4;
            s16x4 vf = *(const s16x4*)&Vt[dt * 16 + q][col];
            a = __builtin_amdgcn_mfma_f32_16x16x16bf16_1k(vf, pb[wt], a, 0, 0, 0);
        }
        oacc[dt] = a;
    }
    __syncthreads();
    float (*Osh)[16][68] = (float (*)[16][68])&Ksh[0][0];
#pragma unroll
    for (int dt = 0; dt < 4; ++dt)
#pragma unroll
        for (int r = 0; r < 4; ++r)
            Osh[wv][q][dt * 16 + g * 4 + r] = oacc[dt][r] * inv;
    __syncthreads();
    const int qq = lane >> 2, dd0 = (lane & 3) * 16;
    u16* op = attb + (size_t)(tw + qq) * 512 + h * 64 + dd0;
#pragma unroll
    for (int jj = 0; jj < 4; ++jj) {
        float4 vvv = *(const float4*)&Osh[wv][qq][dd0 + jj * 4];
        ushort4 ov = { f2b(vvv.x), f2b(vvv.y), f2b(vvv.z), f2b(vvv.w) };
        *(ushort4*)(op + jj * 4) = ov;
    }
}

// ---------------------------------------------------------------------------
// K3: output projection. Same single-barrier double-buffered K-loop; direct
// f32 stores (no epilogue LDS needed).
// ---------------------------------------------------------------------------
__global__ __launch_bounds__(256) void oproj(const u16* __restrict__ A,
    const u16* __restrict__ Bt, float* __restrict__ C)
{
    __shared__ union {
        struct { u16 A[2][64][72]; u16 B[2][64][72]; } d;
    } sh;
    const int tid = threadIdx.x;
    const int m0 = blockIdx.y * 64, n0 = blockIdx.x * 64;
    const int lane = tid & 63, wv = tid >> 6;
    const int q = lane & 15, g = lane >> 4;
    const int wm = (wv & 1) * 32, wn = (wv >> 1) * 32;
    const int sr = tid >> 2, sc = (tid & 3) * 16;
    const u16* Ap = A  + (size_t)(m0 + sr) * 512 + sc;
    const u16* Bp = Bt + (size_t)(n0 + sr) * 512 + sc;
    {
        s16x8 a0 = *(const s16x8*)(Ap);
        s16x8 a1 = *(const s16x8*)(Ap + 8);
        s16x8 b0 = *(const s16x8*)(Bp);
        s16x8 b1 = *(const s16x8*)(Bp + 8);
        *(s16x8*)&sh.d.A[0][sr][sc]     = a0;
        *(s16x8*)&sh.d.A[0][sr][sc + 8] = a1;
        *(s16x8*)&sh.d.B[0][sr][sc]     = b0;
        *(s16x8*)&sh.d.B[0][sr][sc + 8] = b1;
    }
    f32x4 acc[2][2] = {{{0,0,0,0},{0,0,0,0}},{{0,0,0,0},{0,0,0,0}}};
#pragma unroll
    for (int it = 0; it < 8; ++it) {
        const int cur = it & 1;
        __syncthreads();
        s16x8 a0, a1, b0, b1;
        if (it < 7) {
            const u16* An = Ap + (it + 1) * 64;
            const u16* Bn = Bp + (it + 1) * 64;
            a0 = *(const s16x8*)(An);
            a1 = *(const s16x8*)(An + 8);
            b0 = *(const s16x8*)(Bn);
            b1 = *(const s16x8*)(Bn + 8);
        }
#pragma unroll
        for (int kk = 0; kk < 64; kk += 32) {
            s16x8 af0 = *(const s16x8*)&sh.d.A[cur][wm + q][kk + g*8];
            s16x8 af1 = *(const s16x8*)&sh.d.A[cur][wm + 16 + q][kk + g*8];
            s16x8 bf0 = *(const s16x8*)&sh.d.B[cur][wn + q][kk + g*8];
            s16x8 bf1 = *(const s16x8*)&sh.d.B[cur][wn + 16 + q][kk + g*8];
            acc[0][0] = __builtin_amdgcn_mfma_f32_16x16x32_bf16(af0, bf0, acc[0][0], 0, 0, 0);
            acc[0][1] = __builtin_amdgcn_mfma_f32_16x16x32_bf16(af0, bf1, acc[0][1], 0, 0, 0);
            acc[1][0] = __builtin_amdgcn_mfma_f32_16x16x32_bf16(af1, bf0, acc[1][0], 0, 0, 0);
            acc[1][1] = __builtin_amdgcn_mfma_f32_16x16x32_bf16(af1, bf1, acc[1][1], 0, 0, 0);
        }
        if (it < 7) {
            *(s16x8*)&sh.d.A[cur ^ 1][sr][sc]     = a0;
            *(s16x8*)&sh.d.A[cur ^ 1][sr][sc + 8] = a1;
            *(s16x8*)&sh.d.B[cur ^ 1][sr][sc]     = b0;
            *(s16x8*)&sh.d.B[cur ^ 1][sr][sc + 8] = b1;
        }
    }
#pragma unroll
    for (int mt = 0; mt < 2; ++mt)
#pragma unroll
        for (int nt = 0; nt < 2; ++nt)
#pragma unroll
            for (int r = 0; r < 4; ++r)
                C[(size_t)(m0 + wm + mt*16 + g*4 + r) * 512 + n0 + wn + nt*16 + q] = acc[mt][nt][r];
}

// ---------------------------------------------------------------------------
// Workspace: xb [1M u16] | Wt [512K u16] | Wot [256K u16] | qnb [1M] |
//            knb [512K] | vb [512K] | attb [1M]  ≈ 9.5 MB
// ---------------------------------------------------------------------------
extern "C" void kernel_launch(void* const* d_in, const int* in_sizes, int n_in,
                              void* d_out, int out_size, void* d_ws, size_t ws_size,
                              hipStream_t stream)
{
    const float* x    = (const float*)d_in[0];
    const float* Wq   = (const float*)d_in[1];
    const float* Wk   = (const float*)d_in[2];
    const float* Wv   = (const float*)d_in[3];
    const float* Wo   = (const float*)d_in[4];
    const float* qw   = (const float*)d_in[5];
    const float* kw   = (const float*)d_in[6];
    const float* cosT = (const float*)d_in[7];
    const float* sinT = (const float*)d_in[8];

    u16* ws   = (u16*)d_ws;
    u16* xb   = ws;                              // 2048*512
    u16* Wt   = xb   + (size_t)2048 * 512;       // 1024*512
    u16* Wot  = Wt   + (size_t)1024 * 512;       // 512*512
    u16* qnb  = Wot  + (size_t)512 * 512;        // 2048*512
    u16* knb  = qnb  + (size_t)2048 * 512;       // 2048*256
    u16* vb   = knb  + (size_t)2048 * 256;       // 2048*256
    u16* attb = vb   + (size_t)2048 * 256;       // 2048*512

    dim3 blk(256);
    hipLaunchKernelGGL(prep, dim3(704), blk, 0, stream, x, Wq, Wk, Wv, Wo, xb, Wt, Wot);
    hipLaunchKernelGGL(qkv_gemm, dim3(16, 32), blk, 0, stream,
                       xb, Wt, cosT, sinT, qw, kw, qnb, knb, vb);
    hipLaunchKernelGGL(swa_mfma, dim3(32, 8), blk, 0, stream, qnb, knb, vb, attb);
    hipLaunchKernelGGL(oproj, dim3(8, 32), blk, 0, stream, attb, Wot, (float*)d_out);
}

// Round 8
// 47.327 us; speedup vs baseline: 7.9820x; 1.0859x over previous
//
#include <hip/hip_runtime.h>
#include <hip/hip_bf16.h>
#include <math.h>

typedef float  f32x4  __attribute__((ext_vector_type(4)));
typedef short  s16x4  __attribute__((ext_vector_type(4)));
typedef short  s16x8  __attribute__((ext_vector_type(8)));
typedef unsigned short u16;

__device__ inline u16 f2b(float f) {
    __hip_bfloat16 h = __float2bfloat16(f);
    return *reinterpret_cast<u16*>(&h);
}

// ---------------------------------------------------------------------------
// K0: prep (weights only, 192 blocks): transpose-cast -> Wt [1024][512] bf16
// (rows 0-511 Wq^T | 512-767 Wk^T | 768-1023 Wv^T), Wot [512][512] = Wo^T.
// ---------------------------------------------------------------------------
__global__ __launch_bounds__(256) void prep(
    const float* __restrict__ Wq, const float* __restrict__ Wk,
    const float* __restrict__ Wv, const float* __restrict__ Wo,
    u16* __restrict__ Wt, u16* __restrict__ Wot)
{
    const int tid = threadIdx.x, bid = blockIdx.x;
    __shared__ u16 Tsh[64][72];
    const float* src; u16* dst; int N, base, kt, nt;
    if (bid < 64)       { src = Wq; dst = Wt;  N = 512; base = 0;   kt = bid >> 3;       nt = bid & 7; }
    else if (bid < 96)  { src = Wk; dst = Wt;  N = 256; base = 512; kt = (bid-64) >> 2;  nt = (bid-64) & 3; }
    else if (bid < 128) { src = Wv; dst = Wt;  N = 256; base = 768; kt = (bid-96) >> 2;  nt = (bid-96) & 3; }
    else                { src = Wo; dst = Wot; N = 512; base = 0;   kt = (bid-128) >> 3; nt = (bid-128) & 7; }
    const int k0 = kt * 64, n0 = nt * 64;
    const int r = tid >> 2, c0 = (tid & 3) * 16;
#pragma unroll
    for (int j = 0; j < 4; ++j) {
        float4 v = *(const float4*)(src + (size_t)(k0 + r) * N + n0 + c0 + j * 4);
        Tsh[c0 + j*4 + 0][r] = f2b(v.x);
        Tsh[c0 + j*4 + 1][r] = f2b(v.y);
        Tsh[c0 + j*4 + 2][r] = f2b(v.z);
        Tsh[c0 + j*4 + 3][r] = f2b(v.w);
    }
    __syncthreads();
    const int n = tid >> 2, kc = (tid & 3) * 16;
    u16* op = dst + (size_t)(base + n0 + n) * 512 + k0 + kc;
    *(s16x8*)(op)     = *(const s16x8*)&Tsh[n][kc];
    *(s16x8*)(op + 8) = *(const s16x8*)&Tsh[n][kc + 8];
}

// ---------------------------------------------------------------------------
// K1: QKV GEMM + fused RoPE/RMS epilogue. A = x f32, cast->bf16 during
// vectorized staging (row-major, no scatter). B = Wt pre-transposed bf16.
// Plain 2-barrier K-loop (verified fastest structure for this size).
// M=2048, N=1024 (16 n-tiles = heads), K=512, 64x64 tile / 4 waves.
// ---------------------------------------------------------------------------
__global__ __launch_bounds__(256) void qkv_gemm(const float* __restrict__ x,
    const u16* __restrict__ Bt, const float* __restrict__ cosT,
    const float* __restrict__ sinT, const float* __restrict__ qw,
    const float* __restrict__ kw, u16* __restrict__ qnb,
    u16* __restrict__ knb, u16* __restrict__ vb)
{
    __shared__ u16 Ash[64][72];
    __shared__ u16 Bsh[64][72];
    __shared__ float Osh[64][68];
    const int tid = threadIdx.x;
    const int bx = blockIdx.x;
    const int m0 = blockIdx.y * 64, n0b = bx * 64;
    const int lane = tid & 63, wv = tid >> 6;
    const int q = lane & 15, g = lane >> 4;
    const int wm = (wv & 1) * 32, wn = (wv >> 1) * 32;
    const int sr = tid >> 2, sc = (tid & 3) * 16;
    const float* xrow = x + (size_t)(m0 + sr) * 512 + sc;
    const u16*   Brow = Bt + (size_t)(n0b + sr) * 512 + sc;
    f32x4 acc[2][2] = {{{0,0,0,0},{0,0,0,0}},{{0,0,0,0},{0,0,0,0}}};
    for (int k0 = 0; k0 < 512; k0 += 64) {
        float4 a0 = *(const float4*)(xrow + k0);
        float4 a1 = *(const float4*)(xrow + k0 + 4);
        float4 a2 = *(const float4*)(xrow + k0 + 8);
        float4 a3 = *(const float4*)(xrow + k0 + 12);
        s16x8 b0 = *(const s16x8*)(Brow + k0);
        s16x8 b1 = *(const s16x8*)(Brow + k0 + 8);
        s16x8 av0, av1;
        av0[0] = (short)f2b(a0.x); av0[1] = (short)f2b(a0.y);
        av0[2] = (short)f2b(a0.z); av0[3] = (short)f2b(a0.w);
        av0[4] = (short)f2b(a1.x); av0[5] = (short)f2b(a1.y);
        av0[6] = (short)f2b(a1.z); av0[7] = (short)f2b(a1.w);
        av1[0] = (short)f2b(a2.x); av1[1] = (short)f2b(a2.y);
        av1[2] = (short)f2b(a2.z); av1[3] = (short)f2b(a2.w);
        av1[4] = (short)f2b(a3.x); av1[5] = (short)f2b(a3.y);
        av1[6] = (short)f2b(a3.z); av1[7] = (short)f2b(a3.w);
        __syncthreads();   // previous iteration's reads done before overwrite
        *(s16x8*)&Ash[sr][sc]     = av0;
        *(s16x8*)&Ash[sr][sc + 8] = av1;
        *(s16x8*)&Bsh[sr][sc]     = b0;
        *(s16x8*)&Bsh[sr][sc + 8] = b1;
        __syncthreads();
#pragma unroll
        for (int kk = 0; kk < 64; kk += 32) {
            s16x8 af0 = *(const s16x8*)&Ash[wm + q][kk + g*8];
            s16x8 af1 = *(const s16x8*)&Ash[wm + 16 + q][kk + g*8];
            s16x8 bf0 = *(const s16x8*)&Bsh[wn + q][kk + g*8];
            s16x8 bf1 = *(const s16x8*)&Bsh[wn + 16 + q][kk + g*8];
            acc[0][0] = __builtin_amdgcn_mfma_f32_16x16x32_bf16(af0, bf0, acc[0][0], 0, 0, 0);
            acc[0][1] = __builtin_amdgcn_mfma_f32_16x16x32_bf16(af0, bf1, acc[0][1], 0, 0, 0);
            acc[1][0] = __builtin_amdgcn_mfma_f32_16x16x32_bf16(af1, bf0, acc[1][0], 0, 0, 0);
            acc[1][1] = __builtin_amdgcn_mfma_f32_16x16x32_bf16(af1, bf1, acc[1][1], 0, 0, 0);
        }
    }
    __syncthreads();
    // acc -> Osh (row = t within tile, col = d within head)
#pragma unroll
    for (int mt = 0; mt < 2; ++mt)
#pragma unroll
        for (int nt = 0; nt < 2; ++nt)
#pragma unroll
            for (int r = 0; r < 4; ++r)
                Osh[wm + mt*16 + g*4 + r][wn + nt*16 + q] = acc[mt][nt][r];
    __syncthreads();
    // Per-row epilogue: wave wv owns rows wv*16..wv*16+15; lane = d
#pragma unroll 1
    for (int ii = 0; ii < 16; ++ii) {
        const int row = wv * 16 + ii;
        const int t = m0 + row;
        if (bx >= 12) {
            vb[(size_t)t * 256 + (bx - 12) * 64 + lane] = f2b(Osh[row][lane]);
            continue;
        }
        float y = Osh[row][lane];
        float o = Osh[row][lane ^ 32];
        float c = cosT[t * 32 + (lane & 31)];
        float s = sinT[t * 32 + (lane & 31)];
        float r = (lane < 32) ? (y * c - o * s) : (y * c + o * s);
        float ss = r * r;
#pragma unroll
        for (int off = 32; off; off >>= 1) ss += __shfl_xor(ss, off);
        float scale = rsqrtf(ss * (1.0f / 64.0f) + 1e-6f);
        if (bx < 8) qnb[(size_t)t * 512 + bx * 64 + lane]       = f2b(r * scale * qw[lane]);
        else        knb[(size_t)t * 256 + (bx - 8) * 64 + lane] = f2b(r * scale * kw[lane]);
    }
}

// ---------------------------------------------------------------------------
// K2: MFMA sliding-window attention. Vt stride 202 (101 dwords ≡ 5 mod 32,
// odd -> 16 distinct banks across the 16-lane q-group; was 8-way conflict
// at stride 200). Otherwise the verified structure.
// ---------------------------------------------------------------------------
__global__ __launch_bounds__(256) void swa_mfma(const u16* __restrict__ qnb,
    const u16* __restrict__ knb, const u16* __restrict__ vb,
    u16* __restrict__ attb)
{
    __shared__ u16 Ksh[192][72];
    __shared__ u16 Vt[64][202];
    const int tid = threadIdx.x;
    const int h = blockIdx.y, kvh = h >> 1;
    const int t0 = blockIdx.x * 64;
    for (int i = 0; i < 6; ++i) {
        int idx = i * 256 + tid;
        int j = idx >> 3, d0 = (idx & 7) * 8;
        int kt = t0 - 127 + j;
        s16x8 val = {0,0,0,0,0,0,0,0};
        if (kt >= 0) val = *(const s16x8*)(knb + (size_t)kt * 256 + kvh * 64 + d0);
        *(s16x8*)&Ksh[j][d0] = val;
    }
    for (int cch = 0; cch < 6; ++cch) {
        int w  = cch * 32 + (tid & 31);
        int d0 = (tid >> 5) * 8;
        int kt = t0 - 127 + w;
        s16x8 val = {0,0,0,0,0,0,0,0};
        if (kt >= 0) val = *(const s16x8*)(vb + (size_t)kt * 256 + kvh * 64 + d0);
#pragma unroll
        for (int jj = 0; jj < 8; ++jj) Vt[d0 + jj][w] = ((const u16*)&val)[jj];
    }
    __syncthreads();
    const int wv = tid >> 6, lane = tid & 63;
    const int q = lane & 15, g = lane >> 4;
    const int tw = t0 + wv * 16;
    const int t = tw + q;
    const u16* qp = qnb + (size_t)t * 512 + h * 64;
    s16x8 qf0 = *(const s16x8*)(qp + g * 8);
    s16x8 qf1 = *(const s16x8*)(qp + 32 + g * 8);
    float s[9][4];
    float mx = -INFINITY;
    for (int wt = 0; wt < 9; ++wt) {
        int ldsrow = wv * 16 + wt * 16 + q;
        s16x8 kf0 = *(const s16x8*)&Ksh[ldsrow][g * 8];
        s16x8 kf1 = *(const s16x8*)&Ksh[ldsrow][32 + g * 8];
        f32x4 accv = {0, 0, 0, 0};
        accv = __builtin_amdgcn_mfma_f32_16x16x32_bf16(kf0, qf0, accv, 0, 0, 0);
        accv = __builtin_amdgcn_mfma_f32_16x16x32_bf16(kf1, qf1, accv, 0, 0, 0);
#pragma unroll
        for (int r = 0; r < 4; ++r) {
            int woff = wt * 16 + g * 4 + r;
            int key  = tw - 127 + woff;
            bool ok = (woff >= q) && (woff <= q + 127) && (key >= 0);
            float sv = ok ? accv[r] * 0.125f : -INFINITY;
            s[wt][r] = sv;
            mx = fmaxf(mx, sv);
        }
    }
    mx = fmaxf(mx, __shfl_xor(mx, 16));
    mx = fmaxf(mx, __shfl_xor(mx, 32));
    float sum = 0.f;
    s16x4 pb[9];
    for (int wt = 0; wt < 9; ++wt) {
#pragma unroll
        for (int r = 0; r < 4; ++r) {
            float p = __expf(s[wt][r] - mx);
            sum += p;
            pb[wt][r] = (short)f2b(p);
        }
    }
    sum += __shfl_xor(sum, 16);
    sum += __shfl_xor(sum, 32);
    float inv = 1.0f / sum;
    f32x4 oacc[4];
#pragma unroll
    for (int dt = 0; dt < 4; ++dt) {
        f32x4 a = {0, 0, 0, 0};
        for (int wt = 0; wt < 9; ++wt) {
            int col = wv * 16 + wt * 16 + g * 4;
            s16x4 vf = *(const s16x4*)&Vt[dt * 16 + q][col];
            a = __builtin_amdgcn_mfma_f32_16x16x16bf16_1k(vf, pb[wt], a, 0, 0, 0);
        }
        oacc[dt] = a;
    }
    __syncthreads();
    float (*Osh)[16][68] = (float (*)[16][68])&Ksh[0][0];
#pragma unroll
    for (int dt = 0; dt < 4; ++dt)
#pragma unroll
        for (int r = 0; r < 4; ++r)
            Osh[wv][q][dt * 16 + g * 4 + r] = oacc[dt][r] * inv;
    __syncthreads();
    const int qq = lane >> 2, dd0 = (lane & 3) * 16;
    u16* op = attb + (size_t)(tw + qq) * 512 + h * 64 + dd0;
#pragma unroll
    for (int jj = 0; jj < 4; ++jj) {
        float4 vvv = *(const float4*)&Osh[wv][qq][dd0 + jj * 4];
        ushort4 ov = { f2b(vvv.x), f2b(vvv.y), f2b(vvv.z), f2b(vvv.w) };
        *(ushort4*)(op + jj * 4) = ov;
    }
}

// ---------------------------------------------------------------------------
// K3: output projection. C f32 = attb bf16 @ Wot^T (pre-transposed bf16).
// Plain 2-barrier K-loop.
// ---------------------------------------------------------------------------
__global__ __launch_bounds__(256) void oproj(const u16* __restrict__ A,
    const u16* __restrict__ Bt, float* __restrict__ C)
{
    __shared__ u16 Ash[64][72];
    __shared__ u16 Bsh[64][72];
    const int tid = threadIdx.x;
    const int m0 = blockIdx.y * 64, n0 = blockIdx.x * 64;
    const int lane = tid & 63, wv = tid >> 6;
    const int q = lane & 15, g = lane >> 4;
    const int wm = (wv & 1) * 32, wn = (wv >> 1) * 32;
    const int sr = tid >> 2, sc = (tid & 3) * 16;
    f32x4 acc[2][2] = {{{0,0,0,0},{0,0,0,0}},{{0,0,0,0},{0,0,0,0}}};
    for (int k0 = 0; k0 < 512; k0 += 64) {
        s16x8 a0 = *(const s16x8*)(A  + (size_t)(m0 + sr) * 512 + k0 + sc);
        s16x8 a1 = *(const s16x8*)(A  + (size_t)(m0 + sr) * 512 + k0 + sc + 8);
        s16x8 b0 = *(const s16x8*)(Bt + (size_t)(n0 + sr) * 512 + k0 + sc);
        s16x8 b1 = *(const s16x8*)(Bt + (size_t)(n0 + sr) * 512 + k0 + sc + 8);
        __syncthreads();
        *(s16x8*)&Ash[sr][sc]     = a0;
        *(s16x8*)&Ash[sr][sc + 8] = a1;
        *(s16x8*)&Bsh[sr][sc]     = b0;
        *(s16x8*)&Bsh[sr][sc + 8] = b1;
        __syncthreads();
#pragma unroll
        for (int kk = 0; kk < 64; kk += 32) {
            s16x8 af0 = *(const s16x8*)&Ash[wm + q][kk + g*8];
            s16x8 af1 = *(const s16x8*)&Ash[wm + 16 + q][kk + g*8];
            s16x8 bf0 = *(const s16x8*)&Bsh[wn + q][kk + g*8];
            s16x8 bf1 = *(const s16x8*)&Bsh[wn + 16 + q][kk + g*8];
            acc[0][0] = __builtin_amdgcn_mfma_f32_16x16x32_bf16(af0, bf0, acc[0][0], 0, 0, 0);
            acc[0][1] = __builtin_amdgcn_mfma_f32_16x16x32_bf16(af0, bf1, acc[0][1], 0, 0, 0);
            acc[1][0] = __builtin_amdgcn_mfma_f32_16x16x32_bf16(af1, bf0, acc[1][0], 0, 0, 0);
            acc[1][1] = __builtin_amdgcn_mfma_f32_16x16x32_bf16(af1, bf1, acc[1][1], 0, 0, 0);
        }
    }
#pragma unroll
    for (int mt = 0; mt < 2; ++mt)
#pragma unroll
        for (int nt = 0; nt < 2; ++nt)
#pragma unroll
            for (int r = 0; r < 4; ++r)
                C[(size_t)(m0 + wm + mt*16 + g*4 + r) * 512 + n0 + wn + nt*16 + q] = acc[mt][nt][r];
}

// ---------------------------------------------------------------------------
// Workspace: Wt [512K u16] | Wot [256K u16] | qnb [1M] | knb [512K] |
//            vb [512K] | attb [1M]  ≈ 7.5 MB
// ---------------------------------------------------------------------------
extern "C" void kernel_launch(void* const* d_in, const int* in_sizes, int n_in,
                              void* d_out, int out_size, void* d_ws, size_t ws_size,
                              hipStream_t stream)
{
    const float* x    = (const float*)d_in[0];
    const float* Wq   = (const float*)d_in[1];
    const float* Wk   = (const float*)d_in[2];
    const float* Wv   = (const float*)d_in[3];
    const float* Wo   = (const float*)d_in[4];
    const float* qw   = (const float*)d_in[5];
    const float* kw   = (const float*)d_in[6];
    const float* cosT = (const float*)d_in[7];
    const float* sinT = (const float*)d_in[8];

    u16* ws   = (u16*)d_ws;
    u16* Wt   = ws;                              // 1024*512
    u16* Wot  = Wt   + (size_t)1024 * 512;       // 512*512
    u16* qnb  = Wot  + (size_t)512 * 512;        // 2048*512
    u16* knb  = qnb  + (size_t)2048 * 512;       // 2048*256
    u16* vb   = knb  + (size_t)2048 * 256;       // 2048*256
    u16* attb = vb   + (size_t)2048 * 256;       // 2048*512

    dim3 blk(256);
    hipLaunchKernelGGL(prep, dim3(192), blk, 0, stream, Wq, Wk, Wv, Wo, Wt, Wot);
    hipLaunchKernelGGL(qkv_gemm, dim3(16, 32), blk, 0, stream,
                       x, Wt, cosT, sinT, qw, kw, qnb, knb, vb);
    hipLaunchKernelGGL(swa_mfma, dim3(32, 8), blk, 0, stream, qnb, knb, vb, attb);
    hipLaunchKernelGGL(oproj, dim3(8, 32), blk, 0, stream, attb, Wot, (float*)d_out);
}

// Round 9
// 39.692 us; speedup vs baseline: 9.5174x; 1.1924x over previous
//
#include <hip/hip_runtime.h>
#include <hip/hip_bf16.h>
#include <math.h>

typedef float  f32x4  __attribute__((ext_vector_type(4)));
typedef short  s16x4  __attribute__((ext_vector_type(4)));
typedef short  s16x8  __attribute__((ext_vector_type(8)));
typedef unsigned short u16;

__device__ inline u16 f2b(float f) {
    __hip_bfloat16 h = __float2bfloat16(f);
    return *reinterpret_cast<u16*>(&h);
}

// ---------------------------------------------------------------------------
// K0: prep. blocks 0-191: transpose-cast weights -> Wt [1024][512] bf16
// (rows 0-511 Wq^T | 512-767 Wk^T | 768-1023 Wv^T), Wot [512][512] = Wo^T.
// blocks 192-703: cast x -> xb bf16 (8 elems/thread, vectorized).
// ---------------------------------------------------------------------------
__global__ __launch_bounds__(256) void prep(const float* __restrict__ x,
    const float* __restrict__ Wq, const float* __restrict__ Wk,
    const float* __restrict__ Wv, const float* __restrict__ Wo,
    u16* __restrict__ xb, u16* __restrict__ Wt, u16* __restrict__ Wot)
{
    const int tid = threadIdx.x, bid = blockIdx.x;
    if (bid >= 192) {   // x cast
        int i = ((bid - 192) * 256 + tid) * 8;
        float4 v0 = *(const float4*)(x + i);
        float4 v1 = *(const float4*)(x + i + 4);
        ushort4 o0 = { f2b(v0.x), f2b(v0.y), f2b(v0.z), f2b(v0.w) };
        ushort4 o1 = { f2b(v1.x), f2b(v1.y), f2b(v1.z), f2b(v1.w) };
        *(ushort4*)(xb + i)     = o0;
        *(ushort4*)(xb + i + 4) = o1;
        return;
    }
    __shared__ u16 Tsh[64][72];
    const float* src; u16* dst; int N, base, kt, nt;
    if (bid < 64)       { src = Wq; dst = Wt;  N = 512; base = 0;   kt = bid >> 3;       nt = bid & 7; }
    else if (bid < 96)  { src = Wk; dst = Wt;  N = 256; base = 512; kt = (bid-64) >> 2;  nt = (bid-64) & 3; }
    else if (bid < 128) { src = Wv; dst = Wt;  N = 256; base = 768; kt = (bid-96) >> 2;  nt = (bid-96) & 3; }
    else                { src = Wo; dst = Wot; N = 512; base = 0;   kt = (bid-128) >> 3; nt = (bid-128) & 7; }
    const int k0 = kt * 64, n0 = nt * 64;
    const int r = tid >> 2, c0 = (tid & 3) * 16;
#pragma unroll
    for (int j = 0; j < 4; ++j) {
        float4 v = *(const float4*)(src + (size_t)(k0 + r) * N + n0 + c0 + j * 4);
        Tsh[c0 + j*4 + 0][r] = f2b(v.x);
        Tsh[c0 + j*4 + 1][r] = f2b(v.y);
        Tsh[c0 + j*4 + 2][r] = f2b(v.z);
        Tsh[c0 + j*4 + 3][r] = f2b(v.w);
    }
    __syncthreads();
    const int n = tid >> 2, kc = (tid & 3) * 16;
    u16* op = dst + (size_t)(base + n0 + n) * 512 + k0 + kc;
    *(s16x8*)(op)     = *(const s16x8*)&Tsh[n][kc];
    *(s16x8*)(op + 8) = *(const s16x8*)&Tsh[n][kc + 8];
}

// ---------------------------------------------------------------------------
// bf16 MFMA GEMM (verified R3 fast path): C[M x N] f32 = A[M x 512] bf16 @
// Bt[N][512] bf16. 64x64 tile / 4 waves (32x32 each), BK=64, 2-barrier loop,
// pure s16x8 vector staging.
// ---------------------------------------------------------------------------
__global__ __launch_bounds__(256) void gemm_mfma(const u16* __restrict__ A,
    const u16* __restrict__ Bt, float* __restrict__ C, int ldc)
{
    __shared__ u16 Ash[64][72];
    __shared__ u16 Bsh[64][72];
    const int tid = threadIdx.x;
    const int m0b = blockIdx.y * 64, n0b = blockIdx.x * 64;
    const int lane = tid & 63, wv = tid >> 6;
    const int q = lane & 15, g = lane >> 4;
    const int wm = (wv & 1) * 32, wn = (wv >> 1) * 32;
    const int sr = tid >> 2, sc = (tid & 3) * 16;
    f32x4 acc[2][2] = {{{0,0,0,0},{0,0,0,0}},{{0,0,0,0},{0,0,0,0}}};
    for (int k0 = 0; k0 < 512; k0 += 64) {
        s16x8 a0 = *(const s16x8*)(A  + (size_t)(m0b + sr) * 512 + k0 + sc);
        s16x8 a1 = *(const s16x8*)(A  + (size_t)(m0b + sr) * 512 + k0 + sc + 8);
        s16x8 b0 = *(const s16x8*)(Bt + (size_t)(n0b + sr) * 512 + k0 + sc);
        s16x8 b1 = *(const s16x8*)(Bt + (size_t)(n0b + sr) * 512 + k0 + sc + 8);
        __syncthreads();
        *(s16x8*)&Ash[sr][sc]     = a0;
        *(s16x8*)&Ash[sr][sc + 8] = a1;
        *(s16x8*)&Bsh[sr][sc]     = b0;
        *(s16x8*)&Bsh[sr][sc + 8] = b1;
        __syncthreads();
#pragma unroll
        for (int kk = 0; kk < 64; kk += 32) {
            s16x8 af0 = *(const s16x8*)&Ash[wm + q][kk + g*8];
            s16x8 af1 = *(const s16x8*)&Ash[wm + 16 + q][kk + g*8];
            s16x8 bf0 = *(const s16x8*)&Bsh[wn + q][kk + g*8];
            s16x8 bf1 = *(const s16x8*)&Bsh[wn + 16 + q][kk + g*8];
            acc[0][0] = __builtin_amdgcn_mfma_f32_16x16x32_bf16(af0, bf0, acc[0][0], 0, 0, 0);
            acc[0][1] = __builtin_amdgcn_mfma_f32_16x16x32_bf16(af0, bf1, acc[0][1], 0, 0, 0);
            acc[1][0] = __builtin_amdgcn_mfma_f32_16x16x32_bf16(af1, bf0, acc[1][0], 0, 0, 0);
            acc[1][1] = __builtin_amdgcn_mfma_f32_16x16x32_bf16(af1, bf1, acc[1][1], 0, 0, 0);
        }
    }
#pragma unroll
    for (int mt = 0; mt < 2; ++mt)
#pragma unroll
        for (int nt = 0; nt < 2; ++nt)
#pragma unroll
            for (int r = 0; r < 4; ++r)
                C[(size_t)(m0b + wm + mt*16 + g*4 + r) * ldc + n0b + wn + nt*16 + q] = acc[mt][nt][r];
}

// ---------------------------------------------------------------------------
// RoPE + RMS -> bf16 Q/K; V cast -> bf16 (verified R3). One wave per (t,
// unit); units 0-7 q-heads, 8-11 k-heads, 12-15 v-cast. qkv f32 [T][1024].
// ---------------------------------------------------------------------------
__global__ __launch_bounds__(256) void rope_rms_b(const float* __restrict__ qkv,
    const float* __restrict__ cosT, const float* __restrict__ sinT,
    const float* __restrict__ qw, const float* __restrict__ kw,
    u16* __restrict__ qnb, u16* __restrict__ knb, u16* __restrict__ vb)
{
    const int lane = threadIdx.x & 63;
    const int gid  = blockIdx.x * 4 + (threadIdx.x >> 6);
    const int t = gid >> 4, hh = gid & 15;
    if (hh >= 12) {
        int vh = hh - 12;
        vb[(size_t)t * 256 + vh * 64 + lane] =
            f2b(qkv[(size_t)t * 1024 + 768 + vh * 64 + lane]);
        return;
    }
    const float* src; u16* dst; const float* nw;
    if (hh < 8) { src = qkv + (size_t)t*1024 + hh*64;           dst = qnb + (size_t)t*512 + hh*64;     nw = qw; }
    else        { src = qkv + (size_t)t*1024 + 512 + (hh-8)*64; dst = knb + (size_t)t*256 + (hh-8)*64; nw = kw; }
    float y = src[lane];
    float o = __shfl(y, lane ^ 32);
    float c = cosT[t * 32 + (lane & 31)];
    float s = sinT[t * 32 + (lane & 31)];
    float r = (lane < 32) ? (y * c - o * s) : (y * c + o * s);
    float ss = r * r;
#pragma unroll
    for (int off = 32; off; off >>= 1) ss += __shfl_xor(ss, off);
    dst[lane] = f2b(r * rsqrtf(ss * (1.0f/64.0f) + 1e-6f) * nw[lane]);
}

// ---------------------------------------------------------------------------
// swa: MFMA sliding-window attention (verified; Vt stride 202 = odd dword
// stride -> spread banks on PV reads). Block = (h, 64-q tile), 4 waves.
// S^T = K·Q^T (16x16x32); P^T rows land in 16x16x16 k-operand layout;
// O^T = V^T·P^T; LDS transpose out.
// ---------------------------------------------------------------------------
__global__ __launch_bounds__(256) void swa_mfma(const u16* __restrict__ qnb,
    const u16* __restrict__ knb, const u16* __restrict__ vb,
    u16* __restrict__ attb)
{
    __shared__ u16 Ksh[192][72];
    __shared__ u16 Vt[64][202];
    const int tid = threadIdx.x;
    const int h = blockIdx.y, kvh = h >> 1;
    const int t0 = blockIdx.x * 64;
    for (int i = 0; i < 6; ++i) {
        int idx = i * 256 + tid;
        int j = idx >> 3, d0 = (idx & 7) * 8;
        int kt = t0 - 127 + j;
        s16x8 val = {0,0,0,0,0,0,0,0};
        if (kt >= 0) val = *(const s16x8*)(knb + (size_t)kt * 256 + kvh * 64 + d0);
        *(s16x8*)&Ksh[j][d0] = val;
    }
    for (int cch = 0; cch < 6; ++cch) {
        int w  = cch * 32 + (tid & 31);
        int d0 = (tid >> 5) * 8;
        int kt = t0 - 127 + w;
        s16x8 val = {0,0,0,0,0,0,0,0};
        if (kt >= 0) val = *(const s16x8*)(vb + (size_t)kt * 256 + kvh * 64 + d0);
#pragma unroll
        for (int jj = 0; jj < 8; ++jj) Vt[d0 + jj][w] = ((const u16*)&val)[jj];
    }
    __syncthreads();
    const int wv = tid >> 6, lane = tid & 63;
    const int q = lane & 15, g = lane >> 4;
    const int tw = t0 + wv * 16;
    const int t = tw + q;
    const u16* qp = qnb + (size_t)t * 512 + h * 64;
    s16x8 qf0 = *(const s16x8*)(qp + g * 8);
    s16x8 qf1 = *(const s16x8*)(qp + 32 + g * 8);
    float s[9][4];
    float mx = -INFINITY;
    for (int wt = 0; wt < 9; ++wt) {
        int ldsrow = wv * 16 + wt * 16 + q;
        s16x8 kf0 = *(const s16x8*)&Ksh[ldsrow][g * 8];
        s16x8 kf1 = *(const s16x8*)&Ksh[ldsrow][32 + g * 8];
        f32x4 accv = {0, 0, 0, 0};
        accv = __builtin_amdgcn_mfma_f32_16x16x32_bf16(kf0, qf0, accv, 0, 0, 0);
        accv = __builtin_amdgcn_mfma_f32_16x16x32_bf16(kf1, qf1, accv, 0, 0, 0);
#pragma unroll
        for (int r = 0; r < 4; ++r) {
            int woff = wt * 16 + g * 4 + r;
            int key  = tw - 127 + woff;
            bool ok = (woff >= q) && (woff <= q + 127) && (key >= 0);
            float sv = ok ? accv[r] * 0.125f : -INFINITY;
            s[wt][r] = sv;
            mx = fmaxf(mx, sv);
        }
    }
    mx = fmaxf(mx, __shfl_xor(mx, 16));
    mx = fmaxf(mx, __shfl_xor(mx, 32));
    float sum = 0.f;
    s16x4 pb[9];
    for (int wt = 0; wt < 9; ++wt) {
#pragma unroll
        for (int r = 0; r < 4; ++r) {
            float p = __expf(s[wt][r] - mx);
            sum += p;
            pb[wt][r] = (short)f2b(p);
        }
    }
    sum += __shfl_xor(sum, 16);
    sum += __shfl_xor(sum, 32);
    float inv = 1.0f / sum;
    f32x4 oacc[4];
#pragma unroll
    for (int dt = 0; dt < 4; ++dt) {
        f32x4 a = {0, 0, 0, 0};
        for (int wt = 0; wt < 9; ++wt) {
            int col = wv * 16 + wt * 16 + g * 4;
            s16x4 vf = *(const s16x4*)&Vt[dt * 16 + q][col];
            a = __builtin_amdgcn_mfma_f32_16x16x16bf16_1k(vf, pb[wt], a, 0, 0, 0);
        }
        oacc[dt] = a;
    }
    __syncthreads();
    float (*Osh)[16][68] = (float (*)[16][68])&Ksh[0][0];
#pragma unroll
    for (int dt = 0; dt < 4; ++dt)
#pragma unroll
        for (int r = 0; r < 4; ++r)
            Osh[wv][q][dt * 16 + g * 4 + r] = oacc[dt][r] * inv;
    __syncthreads();
    const int qq = lane >> 2, dd0 = (lane & 3) * 16;
    u16* op = attb + (size_t)(tw + qq) * 512 + h * 64 + dd0;
#pragma unroll
    for (int jj = 0; jj < 4; ++jj) {
        float4 vvv = *(const float4*)&Osh[wv][qq][dd0 + jj * 4];
        ushort4 ov = { f2b(vvv.x), f2b(vvv.y), f2b(vvv.z), f2b(vvv.w) };
        *(ushort4*)(op + jj * 4) = ov;
    }
}

// ---------------------------------------------------------------------------
// Workspace: xb [2048*512 u16] | Wt [1024*512] | Wot [512*512] |
//            qkv f32 [2048*1024] | qnb [2048*512] | knb [2048*256] |
//            vb [2048*256] | attb [2048*512]   ≈ 17.5 MB
// ---------------------------------------------------------------------------
extern "C" void kernel_launch(void* const* d_in, const int* in_sizes, int n_in,
                              void* d_out, int out_size, void* d_ws, size_t ws_size,
                              hipStream_t stream)
{
    const float* x    = (const float*)d_in[0];
    const float* Wq   = (const float*)d_in[1];
    const float* Wk   = (const float*)d_in[2];
    const float* Wv   = (const float*)d_in[3];
    const float* Wo   = (const float*)d_in[4];
    const float* qw   = (const float*)d_in[5];
    const float* kw   = (const float*)d_in[6];
    const float* cosT = (const float*)d_in[7];
    const float* sinT = (const float*)d_in[8];

    u16* ws   = (u16*)d_ws;
    u16* xb   = ws;                               // 2048*512
    u16* Wt   = xb  + (size_t)2048 * 512;         // 1024*512
    u16* Wot  = Wt  + (size_t)1024 * 512;         // 512*512
    float* qkv = (float*)(Wot + (size_t)512 * 512);  // 2048*1024 f32 (8B-aligned)
    u16* qnb  = (u16*)(qkv + (size_t)2048 * 1024);   // 2048*512
    u16* knb  = qnb + (size_t)2048 * 512;         // 2048*256
    u16* vb   = knb + (size_t)2048 * 256;         // 2048*256
    u16* attb = vb  + (size_t)2048 * 256;         // 2048*512

    dim3 blk(256);
    hipLaunchKernelGGL(prep, dim3(704), blk, 0, stream, x, Wq, Wk, Wv, Wo, xb, Wt, Wot);
    hipLaunchKernelGGL(gemm_mfma, dim3(16, 32), blk, 0, stream, xb, Wt, qkv, 1024);
    hipLaunchKernelGGL(rope_rms_b, dim3(8192), blk, 0, stream,
                       qkv, cosT, sinT, qw, kw, qnb, knb, vb);
    hipLaunchKernelGGL(swa_mfma, dim3(32, 8), blk, 0, stream, qnb, knb, vb, attb);
    hipLaunchKernelGGL(gemm_mfma, dim3(8, 32), blk, 0, stream, attb, Wot, (float*)d_out, 512);
}